// Round 1
// baseline (1184.798 us; speedup 1.0000x reference)
//
#include <hip/hip_runtime.h>

#define Vn 10000
#define En 60000
#define Bb 8
#define LAT 512
#define HID 256
#define NL 5
#define Mrows (Bb * Vn)   // 80000

__device__ __forceinline__ float4 ld4(const float* p) { return *(const float4*)p; }

// ---------------- graph preprocessing ----------------

__global__ void k_init(int* cnt, int* cur) {
    int i = blockIdx.x * blockDim.x + threadIdx.x;
    if (i < Vn) { cnt[i] = 0; cur[i] = 0; }
}

__global__ void k_count(const int* __restrict__ dst, int* __restrict__ cnt) {
    int e = blockIdx.x * blockDim.x + threadIdx.x;
    if (e < En) atomicAdd(&cnt[dst[e]], 1);
}

__global__ void k_dinv(const int* __restrict__ cnt, float* __restrict__ dinv,
                       float* __restrict__ selfn) {
    int v = blockIdx.x * blockDim.x + threadIdx.x;
    if (v < Vn) {
        float d = (float)cnt[v] + 1.0f;   // +1 self loop
        float r = rsqrtf(d);
        dinv[v] = r;
        selfn[v] = r * r;
    }
}

// exclusive prefix sum of cnt[0..Vn) -> rowptr[0..Vn], single block of 1024
__global__ void k_scan(const int* __restrict__ cnt, int* __restrict__ rowptr) {
    __shared__ int part[1024];
    const int PER = 10;   // 1024*10 >= Vn
    int tid = threadIdx.x;
    int base = tid * PER;
    int local[PER];
    int s = 0;
#pragma unroll
    for (int i = 0; i < PER; ++i) {
        int idx = base + i;
        int c = (idx < Vn) ? cnt[idx] : 0;
        local[i] = s;
        s += c;
    }
    part[tid] = s;
    __syncthreads();
    for (int off = 1; off < 1024; off <<= 1) {
        int add = (tid >= off) ? part[tid - off] : 0;
        __syncthreads();
        part[tid] += add;
        __syncthreads();
    }
    int chunk_base = part[tid] - s;   // exclusive base of this thread's chunk
#pragma unroll
    for (int i = 0; i < PER; ++i) {
        int idx = base + i;
        if (idx < Vn) rowptr[idx] = chunk_base + local[i];
    }
    if (tid == 1023) rowptr[Vn] = part[1023];
}

__global__ void k_fill(const int* __restrict__ src, const int* __restrict__ dst,
                       const float* __restrict__ dinv, const int* __restrict__ rowptr,
                       int* __restrict__ cur, int* __restrict__ csr_src,
                       float* __restrict__ csr_norm) {
    int e = blockIdx.x * blockDim.x + threadIdx.x;
    if (e < En) {
        int s = src[e], d = dst[e];
        int p = atomicAdd(&cur[d], 1);
        int idx = rowptr[d] + p;
        csr_src[idx] = s;
        csr_norm[idx] = dinv[s] * dinv[d];
    }
}

// ---------------- input layer ----------------

// latc[b][h] = input_b[h] + dot(latent[b,:], input_W[h,3:])
__global__ void k_latc(const float* __restrict__ latent, const float* __restrict__ input_W,
                       const float* __restrict__ input_b, float* __restrict__ latc) {
    int i = blockIdx.x * blockDim.x + threadIdx.x;
    if (i < Bb * HID) {
        int b = i / HID, h = i % HID;
        const float* w = input_W + (size_t)h * (LAT + 3) + 3;
        const float* l = latent + (size_t)b * LAT;
        float s = input_b[h];
        for (int k = 0; k < LAT; ++k) s = fmaf(l[k], w[k], s);
        latc[i] = s;
    }
}

// X[b][v][h] = relu(xyz[v]·input_W[h,0:3] + latc[b][h]); one block per (b,v), h = tid
__global__ __launch_bounds__(256) void k_input(const float* __restrict__ xyz,
                                               const float* __restrict__ input_W,
                                               const float* __restrict__ latc,
                                               float* __restrict__ X) {
    int bv = blockIdx.x;
    int h = threadIdx.x;
    int v = bv % Vn;
    int b = bv / Vn;
    const float* w = input_W + (size_t)h * (LAT + 3);
    float x0 = xyz[v * 3 + 0], x1 = xyz[v * 3 + 1], x2 = xyz[v * 3 + 2];
    float s = latc[b * HID + h];
    s = fmaf(x0, w[0], s);
    s = fmaf(x1, w[1], s);
    s = fmaf(x2, w[2], s);
    X[(size_t)bv * HID + h] = fmaxf(s, 0.0f);
}

// ---------------- dense GEMM: C[m][n] = sum_k A[m][k] * W[n][k] ----------------
// A: [Mrows][256] row-major, W: [256][256] row-major (both k-inner, "NT")
// 128x128 block tile, 256 threads, 8x8 per-thread microtile, KT=16

__global__ __launch_bounds__(256) void k_gemm(const float* __restrict__ A,
                                              const float* __restrict__ W,
                                              float* __restrict__ C) {
    __shared__ float As[16][128];
    __shared__ float Bs[16][128];
    const int tid = threadIdx.x;
    const int m0 = blockIdx.x * 128;
    const int n0 = blockIdx.y * 128;
    const int tx = tid & 15;        // n group
    const int ty = tid >> 4;        // m group
    const int lr = tid >> 2;        // loader row (0..63)
    const int lk = (tid & 3) << 2;  // loader k offset (0,4,8,12)

    float acc[8][8];
#pragma unroll
    for (int i = 0; i < 8; ++i)
#pragma unroll
        for (int j = 0; j < 8; ++j) acc[i][j] = 0.0f;

    const float* Arow0 = A + (size_t)(m0 + lr) * HID + lk;
    const float* Arow1 = Arow0 + (size_t)64 * HID;
    const float* Wrow0 = W + (size_t)(n0 + lr) * HID + lk;
    const float* Wrow1 = Wrow0 + (size_t)64 * HID;

    for (int k0 = 0; k0 < HID; k0 += 16) {
        float4 a0 = ld4(Arow0 + k0);
        float4 a1 = ld4(Arow1 + k0);
        float4 b0 = ld4(Wrow0 + k0);
        float4 b1 = ld4(Wrow1 + k0);
        __syncthreads();
        As[lk + 0][lr] = a0.x; As[lk + 1][lr] = a0.y; As[lk + 2][lr] = a0.z; As[lk + 3][lr] = a0.w;
        As[lk + 0][lr + 64] = a1.x; As[lk + 1][lr + 64] = a1.y; As[lk + 2][lr + 64] = a1.z; As[lk + 3][lr + 64] = a1.w;
        Bs[lk + 0][lr] = b0.x; Bs[lk + 1][lr] = b0.y; Bs[lk + 2][lr] = b0.z; Bs[lk + 3][lr] = b0.w;
        Bs[lk + 0][lr + 64] = b1.x; Bs[lk + 1][lr + 64] = b1.y; Bs[lk + 2][lr + 64] = b1.z; Bs[lk + 3][lr + 64] = b1.w;
        __syncthreads();
#pragma unroll
        for (int k = 0; k < 16; ++k) {
            float4 av0 = *(const float4*)&As[k][ty * 8];
            float4 av1 = *(const float4*)&As[k][ty * 8 + 4];
            float4 bv0 = *(const float4*)&Bs[k][tx * 8];
            float4 bv1 = *(const float4*)&Bs[k][tx * 8 + 4];
            float ar[8] = {av0.x, av0.y, av0.z, av0.w, av1.x, av1.y, av1.z, av1.w};
            float br[8] = {bv0.x, bv0.y, bv0.z, bv0.w, bv1.x, bv1.y, bv1.z, bv1.w};
#pragma unroll
            for (int i = 0; i < 8; ++i)
#pragma unroll
                for (int j = 0; j < 8; ++j) acc[i][j] = fmaf(ar[i], br[j], acc[i][j]);
        }
    }

#pragma unroll
    for (int i = 0; i < 8; ++i) {
        float* cp = C + (size_t)(m0 + ty * 8 + i) * HID + n0 + tx * 8;
        float4 o0 = {acc[i][0], acc[i][1], acc[i][2], acc[i][3]};
        float4 o1 = {acc[i][4], acc[i][5], acc[i][6], acc[i][7]};
        *(float4*)cp = o0;
        *(float4*)(cp + 4) = o1;
    }
}

// ---------------- aggregation: Xout[b][v] = relu(selfn[v]*H[b][v] + sum_e norm*H[b][src] + bias) ----
// one wave per (b,v); lane covers 4 features

__global__ __launch_bounds__(256) void k_agg(const float* __restrict__ Hin,
                                             float* __restrict__ Xout,
                                             const float* __restrict__ bias,
                                             const int* __restrict__ rowptr,
                                             const int* __restrict__ csr_src,
                                             const float* __restrict__ csr_norm,
                                             const float* __restrict__ selfn) {
    int wid = threadIdx.x >> 6;
    int lane = threadIdx.x & 63;
    int bv = blockIdx.x * 4 + wid;
    int b = bv / Vn;
    int v = bv - b * Vn;
    int f = lane << 2;
    size_t bbase = (size_t)b * Vn * HID;

    float4 acc = ld4(&Hin[(size_t)bv * HID + f]);
    float sn = selfn[v];
    acc.x *= sn; acc.y *= sn; acc.z *= sn; acc.w *= sn;

    int s = rowptr[v], e = rowptr[v + 1];
    for (int i = s; i < e; ++i) {
        float nrm = csr_norm[i];
        float4 hv = ld4(&Hin[bbase + (size_t)csr_src[i] * HID + f]);
        acc.x = fmaf(nrm, hv.x, acc.x);
        acc.y = fmaf(nrm, hv.y, acc.y);
        acc.z = fmaf(nrm, hv.z, acc.z);
        acc.w = fmaf(nrm, hv.w, acc.w);
    }
    float4 bb = ld4(&bias[f]);
    float4 r;
    r.x = fmaxf(acc.x + bb.x, 0.0f);
    r.y = fmaxf(acc.y + bb.y, 0.0f);
    r.z = fmaxf(acc.z + bb.z, 0.0f);
    r.w = fmaxf(acc.w + bb.w, 0.0f);
    *(float4*)&Xout[(size_t)bv * HID + f] = r;
}

// ---------------- output layer: disp[b][v][c] = dot(X[b][v], out_W[c]) + out_b[c] ----------------

__global__ __launch_bounds__(256) void k_out(const float* __restrict__ X,
                                             const float* __restrict__ oW,
                                             const float* __restrict__ ob,
                                             float* __restrict__ disp) {
    int wid = threadIdx.x >> 6;
    int lane = threadIdx.x & 63;
    int bv = blockIdx.x * 4 + wid;
    int f = lane << 2;
    float4 xv = ld4(&X[(size_t)bv * HID + f]);
    float p[3];
#pragma unroll
    for (int c = 0; c < 3; ++c) {
        float4 wv = ld4(&oW[c * HID + f]);
        p[c] = xv.x * wv.x + xv.y * wv.y + xv.z * wv.z + xv.w * wv.w;
    }
#pragma unroll
    for (int off = 32; off > 0; off >>= 1) {
#pragma unroll
        for (int c = 0; c < 3; ++c) p[c] += __shfl_down(p[c], off, 64);
    }
    if (lane == 0) {
#pragma unroll
        for (int c = 0; c < 3; ++c) disp[(size_t)bv * 3 + c] = p[c] + ob[c];
    }
}

// ---------------- launch ----------------

extern "C" void kernel_launch(void* const* d_in, const int* in_sizes, int n_in,
                              void* d_out, int out_size, void* d_ws, size_t ws_size,
                              hipStream_t stream) {
    const float* xyz     = (const float*)d_in[0];
    const float* latent  = (const float*)d_in[1];
    const int*   eidx    = (const int*)d_in[2];
    const float* input_W = (const float*)d_in[3];
    const float* input_b = (const float*)d_in[4];
    const float* conv_W  = (const float*)d_in[5];
    const float* conv_b  = (const float*)d_in[6];
    const float* out_W   = (const float*)d_in[7];
    const float* out_b   = (const float*)d_in[8];
    float* disp = (float*)d_out;

    const int* src = eidx;
    const int* dst = eidx + En;

    // workspace carve-up (256B aligned)
    char* base = (char*)d_ws;
    size_t off = 0;
    auto alloc = [&](size_t bytes) {
        size_t o = off;
        off = (off + bytes + 255) & ~(size_t)255;
        return (void*)(base + o);
    };
    int*   cnt      = (int*)alloc(Vn * 4);
    int*   cur      = (int*)alloc(Vn * 4);
    float* dinv     = (float*)alloc(Vn * 4);
    float* selfn    = (float*)alloc(Vn * 4);
    int*   rowptr   = (int*)alloc((Vn + 1) * 4);
    int*   csr_src  = (int*)alloc(En * 4);
    float* csr_norm = (float*)alloc(En * 4);
    float* latc     = (float*)alloc(Bb * HID * 4);
    float* X        = (float*)alloc((size_t)Mrows * HID * 4);
    float* Hb       = (float*)alloc((size_t)Mrows * HID * 4);

    // graph preprocessing
    k_init<<<(Vn + 255) / 256, 256, 0, stream>>>(cnt, cur);
    k_count<<<(En + 255) / 256, 256, 0, stream>>>(dst, cnt);
    k_dinv<<<(Vn + 255) / 256, 256, 0, stream>>>(cnt, dinv, selfn);
    k_scan<<<1, 1024, 0, stream>>>(cnt, rowptr);
    k_fill<<<(En + 255) / 256, 256, 0, stream>>>(src, dst, dinv, rowptr, cur, csr_src, csr_norm);

    // input layer
    k_latc<<<(Bb * HID + 255) / 256, 256, 0, stream>>>(latent, input_W, input_b, latc);
    k_input<<<Mrows, 256, 0, stream>>>(xyz, input_W, latc, X);

    // conv layers
    for (int l = 0; l < NL; ++l) {
        dim3 grid(Mrows / 128, HID / 128);
        k_gemm<<<grid, 256, 0, stream>>>(X, conv_W + (size_t)l * HID * HID, Hb);
        k_agg<<<Mrows / 4, 256, 0, stream>>>(Hb, X, conv_b + (size_t)l * HID,
                                             rowptr, csr_src, csr_norm, selfn);
    }

    // output layer
    k_out<<<Mrows / 4, 256, 0, stream>>>(X, out_W, out_b, disp);
}

// Round 6
// 553.145 us; speedup vs baseline: 2.1419x; 2.1419x over previous
//
#include <hip/hip_runtime.h>

#define Vn 10000
#define En 60000
#define Bb 8
#define LAT 512
#define HID 256
#define NL 5
#define Mrows (Bb * Vn)   // 80000

typedef __attribute__((ext_vector_type(4))) int    i32x4;
typedef __attribute__((ext_vector_type(4))) float  f32x4;
typedef __attribute__((ext_vector_type(8))) short  bf16x8;
typedef __attribute__((ext_vector_type(4))) unsigned short u16x4;

__device__ __forceinline__ float bf2f(unsigned short u) {
    union { unsigned int u; float f; } c;
    c.u = ((unsigned int)u) << 16;
    return c.f;
}
__device__ __forceinline__ unsigned short f2bf(float f) {
    union { float f; unsigned int u; } c;
    c.f = f;
    unsigned int u = c.u + 0x7FFFu + ((c.u >> 16) & 1u);  // RNE
    return (unsigned short)(u >> 16);
}

// ---------------- graph preprocessing (fp32/int) ----------------

__global__ void k_init(int* cnt, int* cur) {
    int i = blockIdx.x * blockDim.x + threadIdx.x;
    if (i < Vn) { cnt[i] = 0; cur[i] = 0; }
}

__global__ void k_count(const int* __restrict__ dst, int* __restrict__ cnt) {
    int e = blockIdx.x * blockDim.x + threadIdx.x;
    if (e < En) atomicAdd(&cnt[dst[e]], 1);
}

__global__ void k_dinv(const int* __restrict__ cnt, float* __restrict__ dinv,
                       float* __restrict__ selfn) {
    int v = blockIdx.x * blockDim.x + threadIdx.x;
    if (v < Vn) {
        float d = (float)cnt[v] + 1.0f;   // +1 self loop
        float r = rsqrtf(d);
        dinv[v] = r;
        selfn[v] = r * r;
    }
}

__global__ void k_scan(const int* __restrict__ cnt, int* __restrict__ rowptr) {
    __shared__ int part[1024];
    const int PER = 10;
    int tid = threadIdx.x;
    int base = tid * PER;
    int local[PER];
    int s = 0;
#pragma unroll
    for (int i = 0; i < PER; ++i) {
        int idx = base + i;
        int c = (idx < Vn) ? cnt[idx] : 0;
        local[i] = s;
        s += c;
    }
    part[tid] = s;
    __syncthreads();
    for (int off = 1; off < 1024; off <<= 1) {
        int add = (tid >= off) ? part[tid - off] : 0;
        __syncthreads();
        part[tid] += add;
        __syncthreads();
    }
    int chunk_base = part[tid] - s;
#pragma unroll
    for (int i = 0; i < PER; ++i) {
        int idx = base + i;
        if (idx < Vn) rowptr[idx] = chunk_base + local[i];
    }
    if (tid == 1023) rowptr[Vn] = part[1023];
}

__global__ void k_fill(const int* __restrict__ src, const int* __restrict__ dst,
                       const float* __restrict__ dinv, const int* __restrict__ rowptr,
                       int* __restrict__ cur, int* __restrict__ csr_src,
                       float* __restrict__ csr_norm) {
    int e = blockIdx.x * blockDim.x + threadIdx.x;
    if (e < En) {
        int s = src[e], d = dst[e];
        int p = atomicAdd(&cur[d], 1);
        int idx = rowptr[d] + p;
        csr_src[idx] = s;
        csr_norm[idx] = dinv[s] * dinv[d];
    }
}

// ---------------- weight convert fp32 -> bf16 ----------------

__global__ void k_wcvt(const float* __restrict__ W, unsigned short* __restrict__ Wb, int n) {
    int i = blockIdx.x * blockDim.x + threadIdx.x;
    if (i < n) Wb[i] = f2bf(W[i]);
}

// ---------------- input layer ----------------

__global__ void k_latc(const float* __restrict__ latent, const float* __restrict__ input_W,
                       const float* __restrict__ input_b, float* __restrict__ latc) {
    int i = blockIdx.x * blockDim.x + threadIdx.x;
    if (i < Bb * HID) {
        int b = i / HID, h = i % HID;
        const float* w = input_W + (size_t)h * (LAT + 3) + 3;
        const float* l = latent + (size_t)b * LAT;
        float s = input_b[h];
        for (int k = 0; k < LAT; ++k) s = fmaf(l[k], w[k], s);
        latc[i] = s;
    }
}

__global__ __launch_bounds__(256) void k_input(const float* __restrict__ xyz,
                                               const float* __restrict__ input_W,
                                               const float* __restrict__ latc,
                                               unsigned short* __restrict__ X) {
    int bv = blockIdx.x;
    int h = threadIdx.x;
    int v = bv % Vn;
    int b = bv / Vn;
    const float* w = input_W + (size_t)h * (LAT + 3);
    float x0 = xyz[v * 3 + 0], x1 = xyz[v * 3 + 1], x2 = xyz[v * 3 + 2];
    float s = latc[b * HID + h];
    s = fmaf(x0, w[0], s);
    s = fmaf(x1, w[1], s);
    s = fmaf(x2, w[2], s);
    X[(size_t)bv * HID + h] = f2bf(fmaxf(s, 0.0f));
}

// ---------------- aggregation: Xa[b][v] = selfn[v]*X[b][v] + sum_e norm*X[b][src] ----
// (linear part only; bias+relu fused into GEMM epilogue since S·(X·W)=(S·X)·W)

__global__ __launch_bounds__(256) void k_agg(const unsigned short* __restrict__ Xin,
                                             unsigned short* __restrict__ Xa,
                                             const int* __restrict__ rowptr,
                                             const int* __restrict__ csr_src,
                                             const float* __restrict__ csr_norm,
                                             const float* __restrict__ selfn) {
    int wid = threadIdx.x >> 6;
    int lane = threadIdx.x & 63;
    int bv = blockIdx.x * 4 + wid;
    int b = bv / Vn;
    int v = bv - b * Vn;
    int f = lane << 2;
    size_t bbase = (size_t)b * Vn * HID;

    u16x4 hs = *(const u16x4*)&Xin[(size_t)bv * HID + f];
    float sn = selfn[v];
    float a0 = sn * bf2f(hs[0]), a1 = sn * bf2f(hs[1]);
    float a2 = sn * bf2f(hs[2]), a3 = sn * bf2f(hs[3]);

    int s = rowptr[v], e = rowptr[v + 1];
    int i = s;
    for (; i + 2 <= e; i += 2) {
        float n0 = csr_norm[i], n1 = csr_norm[i + 1];
        int s0 = csr_src[i], s1 = csr_src[i + 1];
        u16x4 h0 = *(const u16x4*)&Xin[bbase + (size_t)s0 * HID + f];
        u16x4 h1 = *(const u16x4*)&Xin[bbase + (size_t)s1 * HID + f];
        a0 = fmaf(n0, bf2f(h0[0]), a0); a1 = fmaf(n0, bf2f(h0[1]), a1);
        a2 = fmaf(n0, bf2f(h0[2]), a2); a3 = fmaf(n0, bf2f(h0[3]), a3);
        a0 = fmaf(n1, bf2f(h1[0]), a0); a1 = fmaf(n1, bf2f(h1[1]), a1);
        a2 = fmaf(n1, bf2f(h1[2]), a2); a3 = fmaf(n1, bf2f(h1[3]), a3);
    }
    if (i < e) {
        float n0 = csr_norm[i];
        u16x4 h0 = *(const u16x4*)&Xin[bbase + (size_t)csr_src[i] * HID + f];
        a0 = fmaf(n0, bf2f(h0[0]), a0); a1 = fmaf(n0, bf2f(h0[1]), a1);
        a2 = fmaf(n0, bf2f(h0[2]), a2); a3 = fmaf(n0, bf2f(h0[3]), a3);
    }
    u16x4 r;
    r[0] = f2bf(a0); r[1] = f2bf(a1); r[2] = f2bf(a2); r[3] = f2bf(a3);
    *(u16x4*)&Xa[(size_t)bv * HID + f] = r;
}

// ---------------- MFMA GEMM: X' = relu(Xa·W^T + b), bf16 in/out, f32 accum ----------------
// Block: 64 M x 256 N, 4 waves; wave = 64M x 64N (4 m-tiles x 4 n-tiles, 16x16x32).
// W fragments register-resident (W is 128KB, L2-hot). A-tile LDS, XOR-swizzled (T2).
// C staged back through the same LDS with the SAME swizzle (both-sides rule).

__global__ __launch_bounds__(256) void k_gemm(const unsigned short* __restrict__ A,
                                              const unsigned short* __restrict__ Wb,
                                              const float* __restrict__ bias,
                                              unsigned short* __restrict__ Xout) {
    __shared__ __align__(16) char smem[32768];
    const int t = threadIdx.x;
    const int w = t >> 6;
    const int l = t & 63;
    const int m0 = blockIdx.x * 64;
    const int n0w = w * 64;
    const int lr = l & 15;   // A row / B col / C col
    const int lg = l >> 4;   // k-group (8 contiguous k per group)

    // B fragments: Bf[nt][ks], lane l holds W[n0w+nt*16+lr][ks*32 + lg*8 + 0..7]
    bf16x8 Bf[4][8];
#pragma unroll
    for (int nt = 0; nt < 4; ++nt) {
        const unsigned short* wp = Wb + (size_t)(n0w + nt * 16 + lr) * HID + lg * 8;
#pragma unroll
        for (int ks = 0; ks < 8; ++ks)
            Bf[nt][ks] = __builtin_bit_cast(bf16x8, *(const i32x4*)(wp + ks * 32));
    }

    // Stage A tile (64 rows x 256 bf16 = 32KB), XOR-swizzled within each 512B row
    {
        const char* src = (const char*)(A + (size_t)m0 * HID);
#pragma unroll
        for (int i = 0; i < 8; ++i) {
            int x = i * 4096 + t * 16;              // linear byte in tile
            i32x4 v = *(const i32x4*)(src + x);     // coalesced 1KB/wave
            int sw = (x & ~511) | ((x & 511) ^ (((x >> 9) & 7) << 4));
            *(i32x4*)(smem + sw) = v;
        }
    }
    __syncthreads();

    f32x4 acc[4][4];
#pragma unroll
    for (int mt = 0; mt < 4; ++mt)
#pragma unroll
        for (int nt = 0; nt < 4; ++nt)
            acc[mt][nt] = (f32x4){0.f, 0.f, 0.f, 0.f};

#pragma unroll
    for (int ks = 0; ks < 8; ++ks) {
#pragma unroll
        for (int mt = 0; mt < 4; ++mt) {
            int row = mt * 16 + lr;
            int colb = ks * 64 + lg * 16;
            int addr = row * 512 + (colb ^ ((row & 7) << 4));
            bf16x8 a = __builtin_bit_cast(bf16x8, *(const i32x4*)(smem + addr));
#pragma unroll
            for (int nt = 0; nt < 4; ++nt)
                acc[mt][nt] = __builtin_amdgcn_mfma_f32_16x16x32_bf16(
                    a, Bf[nt][ks], acc[mt][nt], 0, 0, 0);
        }
    }

    __syncthreads();  // done reading A-LDS; reuse as C staging

    float bnt[4];
#pragma unroll
    for (int nt = 0; nt < 4; ++nt) bnt[nt] = bias[n0w + nt * 16 + lr];

#pragma unroll
    for (int mt = 0; mt < 4; ++mt)
#pragma unroll
        for (int nt = 0; nt < 4; ++nt)
#pragma unroll
            for (int r = 0; r < 4; ++r) {
                int row = mt * 16 + lg * 4 + r;          // C/D: row=(l>>4)*4+reg
                int col = n0w + nt * 16 + lr;            // C/D: col=l&15
                float vv = fmaxf(acc[mt][nt][r] + bnt[nt], 0.0f);
                int addr = row * 512 + (((col * 2) & 511) ^ ((row & 7) << 4));
                *(unsigned short*)(smem + addr) = f2bf(vv);
            }
    __syncthreads();

    char* dstb = (char*)(Xout + (size_t)m0 * HID);
#pragma unroll
    for (int i = 0; i < 8; ++i) {
        int x = i * 4096 + t * 16;
        int sw = (x & ~511) | ((x & 511) ^ (((x >> 9) & 7) << 4));
        *(i32x4*)(dstb + x) = *(const i32x4*)(smem + sw);
    }
}

// ---------------- output layer ----------------

__global__ __launch_bounds__(256) void k_out(const unsigned short* __restrict__ X,
                                             const float* __restrict__ oW,
                                             const float* __restrict__ ob,
                                             float* __restrict__ disp) {
    int wid = threadIdx.x >> 6;
    int lane = threadIdx.x & 63;
    int bv = blockIdx.x * 4 + wid;
    int f = lane << 2;
    u16x4 xv = *(const u16x4*)&X[(size_t)bv * HID + f];
    float x0 = bf2f(xv[0]), x1 = bf2f(xv[1]), x2 = bf2f(xv[2]), x3 = bf2f(xv[3]);
    float p[3];
#pragma unroll
    for (int c = 0; c < 3; ++c) {
        f32x4 wv = *(const f32x4*)&oW[c * HID + f];
        p[c] = x0 * wv[0] + x1 * wv[1] + x2 * wv[2] + x3 * wv[3];
    }
#pragma unroll
    for (int off = 32; off > 0; off >>= 1) {
#pragma unroll
        for (int c = 0; c < 3; ++c) p[c] += __shfl_down(p[c], off, 64);
    }
    if (lane == 0) {
#pragma unroll
        for (int c = 0; c < 3; ++c) disp[(size_t)bv * 3 + c] = p[c] + ob[c];
    }
}

// ---------------- launch ----------------

extern "C" void kernel_launch(void* const* d_in, const int* in_sizes, int n_in,
                              void* d_out, int out_size, void* d_ws, size_t ws_size,
                              hipStream_t stream) {
    const float* xyz     = (const float*)d_in[0];
    const float* latent  = (const float*)d_in[1];
    const int*   eidx    = (const int*)d_in[2];
    const float* input_W = (const float*)d_in[3];
    const float* input_b = (const float*)d_in[4];
    const float* conv_W  = (const float*)d_in[5];
    const float* conv_b  = (const float*)d_in[6];
    const float* out_W   = (const float*)d_in[7];
    const float* out_b   = (const float*)d_in[8];
    float* disp = (float*)d_out;

    const int* src = eidx;
    const int* dst = eidx + En;

    char* base = (char*)d_ws;
    size_t off = 0;
    auto alloc = [&](size_t bytes) {
        size_t o = off;
        off = (off + bytes + 255) & ~(size_t)255;
        return (void*)(base + o);
    };
    int*   cnt      = (int*)alloc(Vn * 4);
    int*   cur      = (int*)alloc(Vn * 4);
    float* dinv     = (float*)alloc(Vn * 4);
    float* selfn    = (float*)alloc(Vn * 4);
    int*   rowptr   = (int*)alloc((Vn + 1) * 4);
    int*   csr_src  = (int*)alloc(En * 4);
    float* csr_norm = (float*)alloc(En * 4);
    float* latc     = (float*)alloc(Bb * HID * 4);
    unsigned short* Wb = (unsigned short*)alloc((size_t)NL * HID * HID * 2);
    unsigned short* X  = (unsigned short*)alloc((size_t)Mrows * HID * 2);
    unsigned short* Xa = (unsigned short*)alloc((size_t)Mrows * HID * 2);

    // graph preprocessing
    k_init<<<(Vn + 255) / 256, 256, 0, stream>>>(cnt, cur);
    k_count<<<(En + 255) / 256, 256, 0, stream>>>(dst, cnt);
    k_dinv<<<(Vn + 255) / 256, 256, 0, stream>>>(cnt, dinv, selfn);
    k_scan<<<1, 1024, 0, stream>>>(cnt, rowptr);
    k_fill<<<(En + 255) / 256, 256, 0, stream>>>(src, dst, dinv, rowptr, cur, csr_src, csr_norm);

    // weights -> bf16
    k_wcvt<<<(NL * HID * HID + 255) / 256, 256, 0, stream>>>(conv_W, Wb, NL * HID * HID);

    // input layer
    k_latc<<<(Bb * HID + 255) / 256, 256, 0, stream>>>(latent, input_W, input_b, latc);
    k_input<<<Mrows, 256, 0, stream>>>(xyz, input_W, latc, X);

    // conv layers: Xa = S·X  then  X = relu(Xa·W^T + b)
    for (int l = 0; l < NL; ++l) {
        k_agg<<<Mrows / 4, 256, 0, stream>>>(X, Xa, rowptr, csr_src, csr_norm, selfn);
        k_gemm<<<Mrows / 64, 256, 0, stream>>>(Xa, Wb + (size_t)l * HID * HID,
                                               conv_b + (size_t)l * HID, X);
    }

    // output layer
    k_out<<<Mrows / 4, 256, 0, stream>>>(X, out_W, out_b, disp);
}